// Round 7
// baseline (493.663 us; speedup 1.0000x reference)
//
#include <hip/hip_runtime.h>
#include <hip/hip_cooperative_groups.h>
#include <cstdint>
#include <cstddef>

namespace cg = cooperative_groups;

typedef __bf16 bf16;
typedef __bf16 bf16x4 __attribute__((ext_vector_type(4)));
typedef __bf16 bf16x8 __attribute__((ext_vector_type(8)));
typedef float f32x4 __attribute__((ext_vector_type(4)));

static constexpr float SCALE_F = 0.35355339059327373f;  // (1024/16)^-0.25

#define AS1 __attribute__((address_space(1)))
#define AS3 __attribute__((address_space(3)))

__device__ __forceinline__ void load_lds16(const void* g, void* l) {
  __builtin_amdgcn_global_load_lds((AS1 void*)g, (AS3 void*)l, 16, 0, 0);
}

// ---------------- shared 256x128-tile GEMM K-loop (double-buffered, good-2-phase) ----------------
// LDS: A(buf) = lds + buf*49152 (256 rows x 128B, XOR-swizzled); B(buf) = A(buf)+32768 (128 rows).
__device__ __forceinline__ void gemm_loop(char* lds, const bf16* __restrict__ A,
                                          const bf16* __restrict__ Bw, int m0, int n0, int tid,
                                          int lane, int wv, f32x4 (&acc)[4][4]) {
  const int g = lane >> 4, lr = lane & 15;
  const int wm = wv >> 1, wn = wv & 1;

  auto stage = [&](int buf, int kt) {
    char* sA = lds + buf * 49152;
    char* sB = sA + 32768;
#pragma unroll
    for (int j = 0; j < 4; ++j) {
      int i = tid + j * 512;
      int r = i >> 3, c = i & 7;
      load_lds16((const char*)(A + (size_t)(m0 + r) * 1024 + kt) + ((c * 16) ^ ((r & 7) << 4)),
                 sA + (size_t)i * 16);
    }
#pragma unroll
    for (int j = 0; j < 2; ++j) {
      int i = tid + j * 512;
      int r = i >> 3, c = i & 7;
      load_lds16((const char*)(Bw + (size_t)(n0 + r) * 1024 + kt) + ((c * 16) ^ ((r & 7) << 4)),
                 sB + (size_t)i * 16);
    }
  };
  auto compute = [&](int buf) {
    char* sA = lds + buf * 49152;
    char* sB = sA + 32768;
    bf16x8 af[4][2], bfr[4][2];
#pragma unroll
    for (int mi = 0; mi < 4; ++mi)
#pragma unroll
      for (int kk = 0; kk < 2; ++kk) {
        int rr = wm * 64 + mi * 16 + lr;
        int w = kk * 64 + g * 16;
        af[mi][kk] = *(const bf16x8*)(sA + (size_t)rr * 128 + (w ^ ((rr & 7) << 4)));
        int r2 = wn * 64 + mi * 16 + lr;
        bfr[mi][kk] = *(const bf16x8*)(sB + (size_t)r2 * 128 + (w ^ ((r2 & 7) << 4)));
      }
#pragma unroll
    for (int kk = 0; kk < 2; ++kk)
#pragma unroll
      for (int mi = 0; mi < 4; ++mi)
#pragma unroll
        for (int ni = 0; ni < 4; ++ni)
          acc[mi][ni] = __builtin_amdgcn_mfma_f32_16x16x32_bf16(af[mi][kk], bfr[ni][kk],
                                                                acc[mi][ni], 0, 0, 0);
  };

  stage(0, 0);
  asm volatile("s_waitcnt vmcnt(0)" ::: "memory");
  __syncthreads();
  int cur = 0;
#pragma unroll 1
  for (int kt = 64; kt < 1024; kt += 64) {
    stage(cur ^ 1, kt);   // issue next-tile loads FIRST (latency hides under compute)
    compute(cur);
    asm volatile("s_waitcnt vmcnt(0)" ::: "memory");
    __syncthreads();
    cur ^= 1;
  }
  compute(cur);
}

// ---------------- attention v4 pieces (unchanged from R4) ----------------
struct Frags {
  bf16x8 ka[2][2];
  bf16x8 va[4];
};

__device__ __forceinline__ void load_frags(Frags& f, const char* lds, int G, int lr, int g) {
  const int swz = (lr & 7) << 4;
#pragma unroll
  for (int m = 0; m < 2; ++m)
#pragma unroll
    for (int kk = 0; kk < 2; ++kk)
      f.ka[m][kk] =
          *(const bf16x8*)(lds + (size_t)(G * 32 + m * 16 + lr) * 128 + ((kk * 64 + g * 16) ^ swz));
#pragma unroll
  for (int db = 0; db < 4; ++db)
    f.va[db] = *(const bf16x8*)(lds + 65536 + (size_t)(db * 16 + lr) * 1024 +
                                ((G * 64 + g * 16) ^ swz));
}

__device__ __forceinline__ void compute_group(const Frags& f, const bf16x8 (&qf)[4][2],
                                              f32x4 (&oacc)[4][4], float (&psum)[4]) {
  f32x4 sa[4][2] = {};
#pragma unroll
  for (int s = 0; s < 4; ++s)
#pragma unroll
    for (int m = 0; m < 2; ++m) {
      sa[s][m] = __builtin_amdgcn_mfma_f32_16x16x32_bf16(f.ka[m][0], qf[s][0], sa[s][m], 0, 0, 0);
      sa[s][m] = __builtin_amdgcn_mfma_f32_16x16x32_bf16(f.ka[m][1], qf[s][1], sa[s][m], 0, 0, 0);
    }
  bf16x8 pb[4];
#pragma unroll
  for (int s = 0; s < 4; ++s)
#pragma unroll
    for (int m = 0; m < 2; ++m)
#pragma unroll
      for (int j = 0; j < 4; ++j) {
        float p = __expf(sa[s][m][j] - 16.0f);
        psum[s] += p;
        pb[s][m * 4 + j] = (bf16)p;
      }
#pragma unroll
  for (int s = 0; s < 4; ++s)
#pragma unroll
    for (int db = 0; db < 4; ++db)
      oacc[s][db] = __builtin_amdgcn_mfma_f32_16x16x32_bf16(f.va[db], pb[s], oacc[s][db], 0, 0, 0);
}

__device__ __forceinline__ void attn_stage(char* lds, int bix, int tid,
                                           const bf16* __restrict__ Q,
                                           const bf16* __restrict__ Kw,
                                           const bf16* __restrict__ Vt, bf16* __restrict__ Y) {
  const int lane = tid & 63;
  const int wv = tid >> 6;
  const int g = lane >> 4, lr = lane & 15;
  const int b = bix >> 6, h = (bix >> 2) & 15, tc = bix & 3;

  const bf16* Kh = Kw + (size_t)h * 512 * 64;
  const bf16* Vh = Vt + (size_t)h * 64 * 512;
#pragma unroll
  for (int j = 0; j < 8; ++j) {
    int i = tid + j * 512;
    int r = i >> 3, c = i & 7;
    load_lds16((const char*)Kh + r * 128 + ((c * 16) ^ ((r & 7) << 4)), lds + (size_t)i * 16);
  }
#pragma unroll
  for (int j = 0; j < 8; ++j) {
    int i = tid + j * 512;
    int r = i >> 6, c = i & 63;
    load_lds16((const char*)Vh + r * 1024 + ((c * 16) ^ ((r & 7) << 4)),
               lds + 65536 + (size_t)i * 16);
  }

  const int tb = tc * 512 + wv * 64;
  const bf16* Qh = Q + ((size_t)(b * 16 + h) * 2048 + tb) * 64;
  bf16x8 qf[4][2];
#pragma unroll
  for (int s = 0; s < 4; ++s)
#pragma unroll
    for (int kk = 0; kk < 2; ++kk)
      qf[s][kk] = *(const bf16x8*)((const char*)Qh + (s * 16 + lr) * 128 + kk * 64 + g * 16);

  asm volatile("s_waitcnt vmcnt(0)" ::: "memory");
  __syncthreads();

  f32x4 oacc[4][4] = {};
  float psum[4] = {};

  Frags fA, fB;
  load_frags(fA, lds, 0, lr, g);
#pragma unroll 1
  for (int G = 0; G < 16; G += 2) {
    load_frags(fB, lds, G + 1, lr, g);
    compute_group(fA, qf, oacc, psum);
    if (G + 2 < 16) load_frags(fA, lds, G + 2, lr, g);
    compute_group(fB, qf, oacc, psum);
  }

#pragma unroll
  for (int s = 0; s < 4; ++s) {
    float ssum = psum[s];
    ssum += __shfl_xor(ssum, 16);
    ssum += __shfl_xor(ssum, 32);
    float inv = 1.0f / ssum;
    int t = tb + s * 16 + lr;
    char* yrow = (char*)Y + ((size_t)(b * 2048 + t) * 1024 + h * 64) * 2;
#pragma unroll
    for (int db = 0; db < 4; ++db) {
      bf16x4 w;
#pragma unroll
      for (int j = 0; j < 4; ++j) w[j] = (bf16)(oacc[s][db][j] * inv);
      *(bf16x4*)(yrow + (db * 16 + g * 4) * 2) = w;
    }
  }
}

// ---------------- the cooperative mega-kernel ----------------
__global__ __launch_bounds__(512, 2) void mega(
    const float* __restrict__ inpt, const float* __restrict__ aux, const float* __restrict__ q_w,
    const float* __restrict__ q_b, const float* __restrict__ kv_w, const float* __restrict__ kv_b,
    const float* __restrict__ out_w, const float* __restrict__ out_b, float* __restrict__ out,
    bf16* __restrict__ X, bf16* __restrict__ Qb, bf16* __restrict__ qwb, bf16* __restrict__ owb,
    bf16* __restrict__ Kws, bf16* __restrict__ Vtw) {
  __shared__ __align__(16) char lds[131072];
  const int tid = threadIdx.x;
  const int bix = blockIdx.x;
  const int lane = tid & 63, wv = tid >> 6;
  const int g = lane >> 4, lr = lane & 15;
  const int wm = wv >> 1, wn = wv & 1;
  cg::grid_group grid = cg::this_grid();

  // ===== S0: blocks 224..255 -> KV GEMM from f32; blocks 0..223 -> cvt + transpose =====
  if (bix >= 224) {
    const int kb = bix - 224;  // 0..31
    const int m0 = (kb & 1) * 256, n0 = (kb >> 1) * 128;
    char* sA = lds;           // 256 x 128B bf16, swizzled
    char* sB = lds + 32768;   // 128 x 128B
    f32x4 acc[4][4] = {};
#pragma unroll 1
    for (int kt = 0; kt < 1024; kt += 64) {
#pragma unroll
      for (int j = 0; j < 8; ++j) {
        int i = tid + j * 512;
        int r = i >> 4, c4 = i & 15;
        f32x4 v = *(const f32x4*)(aux + (size_t)(m0 + r) * 1024 + kt + c4 * 4);
        bf16x4 o;
#pragma unroll
        for (int e = 0; e < 4; ++e) o[e] = (bf16)v[e];
        *(bf16x4*)(sA + (size_t)r * 128 + ((c4 * 8) ^ ((r & 7) << 4))) = o;
      }
#pragma unroll
      for (int j = 0; j < 4; ++j) {
        int i = tid + j * 512;
        int r = i >> 4, c4 = i & 15;
        f32x4 v = *(const f32x4*)(kv_w + (size_t)(n0 + r) * 1024 + kt + c4 * 4);
        bf16x4 o;
#pragma unroll
        for (int e = 0; e < 4; ++e) o[e] = (bf16)v[e];
        *(bf16x4*)(sB + (size_t)r * 128 + ((c4 * 8) ^ ((r & 7) << 4))) = o;
      }
      __syncthreads();
      bf16x8 af[4][2], bfr[4][2];
#pragma unroll
      for (int mi = 0; mi < 4; ++mi)
#pragma unroll
        for (int kk = 0; kk < 2; ++kk) {
          int rr = wm * 64 + mi * 16 + lr;
          int w = kk * 64 + g * 16;
          af[mi][kk] = *(const bf16x8*)(sA + (size_t)rr * 128 + (w ^ ((rr & 7) << 4)));
          int r2 = wn * 64 + mi * 16 + lr;
          bfr[mi][kk] = *(const bf16x8*)(sB + (size_t)r2 * 128 + (w ^ ((r2 & 7) << 4)));
        }
#pragma unroll
      for (int kk = 0; kk < 2; ++kk)
#pragma unroll
        for (int mi = 0; mi < 4; ++mi)
#pragma unroll
          for (int ni = 0; ni < 4; ++ni)
            acc[mi][ni] = __builtin_amdgcn_mfma_f32_16x16x32_bf16(af[mi][kk], bfr[ni][kk],
                                                                  acc[mi][ni], 0, 0, 0);
      __syncthreads();
    }
    float bs[4];
#pragma unroll
    for (int ni = 0; ni < 4; ++ni) bs[ni] = kv_b[n0 + wn * 64 + ni * 16 + lr];
#pragma unroll
    for (int mi = 0; mi < 4; ++mi)
#pragma unroll
      for (int ni = 0; ni < 4; ++ni)
#pragma unroll
        for (int j = 0; j < 4; ++j) {
          int row = wm * 64 + mi * 16 + g * 4 + j;
          int col = wn * 64 + ni * 16 + lr;
          int m = m0 + row, n = n0 + col;
          float val = acc[mi][ni][j] + bs[ni];
          if (n < 1024) {
            int hh = n >> 6, d = n & 63;
            Kws[(((size_t)hh * 512 + m) << 6) + d] = (bf16)(val * SCALE_F);
          } else {
            int n2 = n - 1024;
            int hh = n2 >> 6, d = n2 & 63;
            int sl = (m & 0x1E0) | (((m >> 2) & 3) << 3) | (((m >> 4) & 1) << 2) | (m & 3);
            Vtw[(((size_t)hh * 64 + d) << 9) + sl] = (bf16)val;
          }
        }
  } else {
    // cvt q_w/out_w -> bf16 (524288 f32x4 units over 224 blocks)
#pragma unroll 1
    for (int it = 0; it < 5; ++it) {
      int u = bix * 512 + tid + it * 114688;
      if (u < 524288) {
        const float* s = u < 262144 ? q_w : out_w;
        bf16* d = u < 262144 ? qwb : owb;
        int off = u < 262144 ? u : u - 262144;
        float4 v = reinterpret_cast<const float4*>(s)[off];
        bf16x4 o;
        o[0] = (bf16)v.x; o[1] = (bf16)v.y; o[2] = (bf16)v.z; o[3] = (bf16)v.w;
        reinterpret_cast<bf16x4*>(d)[off] = o;
      }
    }
    // transpose inpt (B,C,T) -> X (B*T,C): 8192 32x32 tiles, 2 teams/block
    const int team = tid >> 8, ttid = tid & 255;
    const int tx = ttid & 31, ty = ttid >> 5;
    float* tile = (float*)(lds + team * 4352);  // 32x33 f32
#pragma unroll 1
    for (int it = 0; it < 19; ++it) {
      int tix = bix * 2 + team + it * 448;
      bool act = tix < 8192;
      int b = tix >> 11, rem = tix & 2047;
      int c0 = (rem >> 6) * 32, t0 = (rem & 63) * 32;
      if (act) {
        const float* src = inpt + ((size_t)b * 1024 + c0) * 2048 + t0;
#pragma unroll
        for (int i = 0; i < 4; ++i)
          tile[(ty + i * 8) * 33 + tx] = src[(size_t)(ty + i * 8) * 2048 + tx];
      }
      __syncthreads();
      if (act) {
        bf16* dst = X + ((size_t)b * 2048 + t0) * 1024 + c0;
#pragma unroll
        for (int i = 0; i < 4; ++i)
          dst[(size_t)(ty + i * 8) * 1024 + tx] = (bf16)tile[tx * 33 + ty + i * 8];
      }
      __syncthreads();
    }
  }
  __threadfence();
  grid.sync();

  // ===== S1: Q-proj (256x128 tiles; mt=bix&31 keeps 4 A-panels + full B per XCD L2) =====
  {
    const int m0 = (bix & 31) * 256, n0 = (bix >> 5) * 128;
    f32x4 acc[4][4] = {};
    gemm_loop(lds, X, qwb, m0, n0, tid, lane, wv, acc);
    float bs[4];
#pragma unroll
    for (int ni = 0; ni < 4; ++ni) bs[ni] = q_b[n0 + wn * 64 + ni * 16 + lr];
#pragma unroll
    for (int mi = 0; mi < 4; ++mi)
#pragma unroll
      for (int ni = 0; ni < 4; ++ni)
#pragma unroll
        for (int j = 0; j < 4; ++j) {
          int row = wm * 64 + mi * 16 + g * 4 + j;
          int col = wn * 64 + ni * 16 + lr;
          int m = m0 + row, n = n0 + col;
          float val = (acc[mi][ni][j] + bs[ni]) * SCALE_F;
          int bb = m >> 11, t = m & 2047, hh = n >> 6, d = n & 63;
          Qb[(((size_t)(bb * 16 + hh) * 2048 + t) << 6) + d] = (bf16)val;
        }
  }
  __threadfence();
  grid.sync();

  // ===== S2: attention (Y reuses X) =====
  attn_stage(lds, bix, tid, Qb, Kws, Vtw, X);
  __threadfence();
  grid.sync();

  // ===== S3: out-proj + residual =====
  {
    const int m0 = (bix & 31) * 256, n0 = (bix >> 5) * 128;
    f32x4 acc[4][4] = {};
    gemm_loop(lds, X, owb, m0, n0, tid, lane, wv, acc);
    __syncthreads();  // all ds_reads of final compute done before epilogue overwrite

    float bs[4];
#pragma unroll
    for (int ni = 0; ni < 4; ++ni) bs[ni] = out_b[n0 + wn * 64 + ni * 16 + lr];

    // acc -> LDS [c 128 rows][256 t f32 = 1024B], XOR-swizzled by (c&15)<<4
#pragma unroll
    for (int mi = 0; mi < 4; ++mi)
#pragma unroll
      for (int ni = 0; ni < 4; ++ni) {
        int c_l = wn * 64 + ni * 16 + lr;
        int tbyt = (wm * 64 + mi * 16 + g * 4) * 4;
        f32x4 v;
#pragma unroll
        for (int j = 0; j < 4; ++j) v[j] = acc[mi][ni][j] + bs[ni];
        *(f32x4*)(lds + (size_t)c_l * 1024 + (tbyt ^ ((c_l & 15) << 4))) = v;
      }
    __syncthreads();

    const int b = m0 >> 11, m0t = m0 & 2047;
#pragma unroll
    for (int q = 0; q < 16; ++q) {
      int idx = tid + q * 512;
      int c = idx >> 6, ch = idx & 63;
      f32x4 z = *(const f32x4*)(lds + (size_t)c * 1024 + ((ch * 16) ^ ((c & 15) << 4)));
      size_t fi = ((size_t)b * 1024 + n0 + c) * 2048 + m0t + ch * 4;
      f32x4 iv = *(const f32x4*)(inpt + fi);
      f32x4 w;
#pragma unroll
      for (int j = 0; j < 4; ++j) w[j] = iv[j] + z[j];
      *(f32x4*)(out + fi) = w;
    }
  }
}

// ---------------- launch ----------------

extern "C" void kernel_launch(void* const* d_in, const int* in_sizes, int n_in, void* d_out,
                              int out_size, void* d_ws, size_t ws_size, hipStream_t stream) {
  const float* inpt = (const float*)d_in[0];
  const float* aux = (const float*)d_in[1];
  const float* q_w = (const float*)d_in[2];
  const float* q_b = (const float*)d_in[3];
  const float* kv_w = (const float*)d_in[4];
  const float* kv_b = (const float*)d_in[5];
  const float* out_w = (const float*)d_in[6];
  const float* out_b = (const float*)d_in[7];
  float* out = (float*)d_out;
  char* ws = (char*)d_ws;
  bf16* X = (bf16*)(ws + 0);               // 16MB: X ; reused as attn-out Y
  bf16* Qb = (bf16*)(ws + (16u << 20));    // 16MB: Q (B,H,T,D)
  bf16* qwb = (bf16*)(ws + (32u << 20));   // 2MB
  bf16* owb = (bf16*)(ws + (34u << 20));   // 2MB
  bf16* Kws = (bf16*)(ws + (36u << 20));   // 1MB (H,L,D)
  bf16* Vtw = (bf16*)(ws + (37u << 20));   // 1MB (H,D,L) permuted slots

  void* args[] = {(void*)&inpt, (void*)&aux,  (void*)&q_w, (void*)&q_b, (void*)&kv_w,
                  (void*)&kv_b, (void*)&out_w, (void*)&out_b, (void*)&out, (void*)&X,
                  (void*)&Qb,   (void*)&qwb,  (void*)&owb, (void*)&Kws, (void*)&Vtw};
  hipLaunchCooperativeKernel((void*)mega, dim3(256), dim3(512), args, 0, stream);
}

// Round 9
// 286.844 us; speedup vs baseline: 1.7210x; 1.7210x over previous
//
#include <hip/hip_runtime.h>
#include <cstdint>
#include <cstddef>

typedef __bf16 bf16;
typedef __bf16 bf16x4 __attribute__((ext_vector_type(4)));
typedef __bf16 bf16x8 __attribute__((ext_vector_type(8)));
typedef float f32x4 __attribute__((ext_vector_type(4)));

static constexpr float SCALE_F = 0.35355339059327373f;  // (1024/16)^-0.25

#define AS1 __attribute__((address_space(1)))
#define AS3 __attribute__((address_space(3)))

__device__ __forceinline__ void load_lds16(const void* g, void* l) {
  __builtin_amdgcn_global_load_lds((AS1 void*)g, (AS3 void*)l, 16, 0, 0);
}

// ---------------- prep: f32->bf16 converts (q_w, out_w) + input transpose ----------------
// blocks [0,2048): cvt; blocks [2048,10240): inpt (B,C,T) f32 -> X (B*T,C) bf16
__global__ void prep(const float* __restrict__ q_w, bf16* __restrict__ qwb,
                     const float* __restrict__ out_w, bf16* __restrict__ owb,
                     const float* __restrict__ inpt, bf16* __restrict__ X) {
  const int bid = blockIdx.x;
  const int tid = threadIdx.x;
  if (bid < 2048) {
    int i = bid * 256 + tid;  // float4 index, [0, 524288)
    const float* src;
    bf16* dst;
    int off;
    if (i < 262144) { src = q_w; dst = qwb; off = i; }
    else { src = out_w; dst = owb; off = i - 262144; }
    float4 v = reinterpret_cast<const float4*>(src)[off];
    bf16x4 o;
    o[0] = (bf16)v.x; o[1] = (bf16)v.y; o[2] = (bf16)v.z; o[3] = (bf16)v.w;
    reinterpret_cast<bf16x4*>(dst)[off] = o;
  } else {
    __shared__ float tile[32][33];
    int tb = bid - 2048;          // 0..8191
    int b = tb >> 11;             // batch
    int rem = tb & 2047;
    int c0 = (rem >> 6) * 32;     // c-tile 0..31
    int t0 = (rem & 63) * 32;     // t-tile 0..63
    int tx = tid & 31, ty = tid >> 5;  // 32x8
    const float* src = inpt + ((size_t)b * 1024 + c0) * 2048 + t0;
#pragma unroll
    for (int i = 0; i < 4; ++i) tile[ty + i * 8][tx] = src[(size_t)(ty + i * 8) * 2048 + tx];
    __syncthreads();
    bf16* dst = X + ((size_t)b * 2048 + t0) * 1024 + c0;
#pragma unroll
    for (int i = 0; i < 4; ++i) dst[(size_t)(ty + i * 8) * 1024 + tx] = (bf16)tile[tx][ty + i * 8];
  }
}

// ---------------- standalone KV GEMM: (aux @ kv_w^T + kv_b), f32 inputs ----------------
// 64 blocks: m0 = (bid&3)*128 over L=512, n0 = (bid>>2)*128 over N=2048.
// V epilogue writes Vt with PERMUTED key order: slot = G*32 + gq*8 + m*4 + j
// (key = G*32 + m*16 + gq*4 + j). Softmax sums over keys -> any fixed permutation
// is exact; this one makes P (as produced in-lane by swapped QK^T) directly the
// B-operand of the PV 16x16x32 MFMA. K stays in natural order.
__global__ __launch_bounds__(256, 2) void gemm_kv(const float* __restrict__ aux,
                                                  const float* __restrict__ kv_w,
                                                  const float* __restrict__ kv_b,
                                                  bf16* __restrict__ Kout,
                                                  bf16* __restrict__ Vout) {
  __shared__ __align__(16) char sA[16384];  // 128 x 64 bf16, XOR-swizzled rows
  __shared__ __align__(16) char sB[16384];
  const int tid = threadIdx.x;
  const int lane = tid & 63;
  const int wave = tid >> 6;
  const int wm = wave >> 1, wn = wave & 1;
  const int m0 = (blockIdx.x & 3) * 128, n0 = (blockIdx.x >> 2) * 128;
  f32x4 acc[4][4] = {};

  for (int kt = 0; kt < 1024; kt += 64) {
    // reg-staged f32 -> bf16 -> swizzled LDS (rows contiguous in K: coalesced)
#pragma unroll
    for (int j = 0; j < 8; ++j) {
      int v = tid + j * 256;           // 0..2047
      int r = v >> 4, cq = v & 15;     // row, f32x4-col
      f32x4 a4 = *(const f32x4*)(aux + (size_t)(m0 + r) * 1024 + kt + cq * 4);
      bf16x4 o;
#pragma unroll
      for (int e = 0; e < 4; ++e) o[e] = (bf16)a4[e];
      *(bf16x4*)(sA + (size_t)r * 128 + ((cq * 8) ^ ((r & 7) << 4))) = o;
    }
#pragma unroll
    for (int j = 0; j < 8; ++j) {
      int v = tid + j * 256;
      int r = v >> 4, cq = v & 15;
      f32x4 b4 = *(const f32x4*)(kv_w + (size_t)(n0 + r) * 1024 + kt + cq * 4);
      bf16x4 o;
#pragma unroll
      for (int e = 0; e < 4; ++e) o[e] = (bf16)b4[e];
      *(bf16x4*)(sB + (size_t)r * 128 + ((cq * 8) ^ ((r & 7) << 4))) = o;
    }
    __syncthreads();
    bf16x8 af[4][2], bfr[4][2];
#pragma unroll
    for (int mi = 0; mi < 4; ++mi)
#pragma unroll
      for (int kk = 0; kk < 2; ++kk) {
        int rr = wm * 64 + mi * 16 + (lane & 15);
        int w = kk * 64 + ((lane >> 4) << 4);
        af[mi][kk] = *(const bf16x8*)(sA + (size_t)rr * 128 + (w ^ ((rr & 7) << 4)));
        int r2 = wn * 64 + mi * 16 + (lane & 15);
        bfr[mi][kk] = *(const bf16x8*)(sB + (size_t)r2 * 128 + (w ^ ((r2 & 7) << 4)));
      }
#pragma unroll
    for (int kk = 0; kk < 2; ++kk)
#pragma unroll
      for (int mi = 0; mi < 4; ++mi)
#pragma unroll
        for (int ni = 0; ni < 4; ++ni)
          acc[mi][ni] =
              __builtin_amdgcn_mfma_f32_16x16x32_bf16(af[mi][kk], bfr[ni][kk], acc[mi][ni], 0, 0, 0);
    __syncthreads();
  }

  float bs[4];
#pragma unroll
  for (int ni = 0; ni < 4; ++ni) bs[ni] = kv_b[n0 + wn * 64 + ni * 16 + (lane & 15)];
#pragma unroll
  for (int mi = 0; mi < 4; ++mi)
#pragma unroll
    for (int ni = 0; ni < 4; ++ni)
#pragma unroll
      for (int j = 0; j < 4; ++j) {
        int row = wm * 64 + mi * 16 + ((lane >> 4) << 2) + j;
        int col = wn * 64 + ni * 16 + (lane & 15);
        int m = m0 + row, n = n0 + col;
        float val = acc[mi][ni][j] + bs[ni];
        if (n < 1024) {
          int hh = n >> 6, d = n & 63;
          Kout[(((size_t)hh * 512 + m) << 6) + d] = (bf16)(val * SCALE_F);
        } else {
          int n2 = n - 1024;
          int hh = n2 >> 6, d = n2 & 63;
          int sl = (m & 0x1E0) | (((m >> 2) & 3) << 3) | (((m >> 4) & 1) << 2) | (m & 3);
          Vout[(((size_t)hh * 64 + d) << 9) + sl] = (bf16)val;
        }
      }
}

// ---------------- Q-proj GEMM (R5-proven path, bf16 staged via global_load_lds) ----------------
__global__ __launch_bounds__(256, 3) void gemm_q(const bf16* __restrict__ X,
                                                 const bf16* __restrict__ qwb,
                                                 const float* __restrict__ q_b,
                                                 bf16* __restrict__ Qout) {
  __shared__ __align__(16) char sA[16384];  // 128 x 64 bf16, XOR-swizzled rows
  __shared__ __align__(16) char sB[16384];
  const int tid = threadIdx.x;
  const int lane = tid & 63;
  const int wave = tid >> 6;
  const int wm = wave >> 1, wn = wave & 1;
  const int bid = blockIdx.x;
  const int m0 = (bid >> 3) * 128, n0 = (bid & 7) * 128;
  f32x4 acc[4][4] = {};

  for (int kt = 0; kt < 1024; kt += 64) {
#pragma unroll
    for (int j = 0; j < 4; ++j) {
      int i = tid + j * 256;
      int r = i >> 3, q = i & 7;
      int so = (q ^ (r & 7)) << 4;
      load_lds16((const char*)(X + (size_t)(m0 + r) * 1024 + kt) + so, sA + (size_t)i * 16);
      load_lds16((const char*)(qwb + (size_t)(n0 + r) * 1024 + kt) + so, sB + (size_t)i * 16);
    }
    asm volatile("s_waitcnt vmcnt(0)" ::: "memory");
    __syncthreads();
    bf16x8 af[4][2], bfr[4][2];
#pragma unroll
    for (int mi = 0; mi < 4; ++mi)
#pragma unroll
      for (int kk = 0; kk < 2; ++kk) {
        int rr = wm * 64 + mi * 16 + (lane & 15);
        int w = kk * 64 + ((lane >> 4) << 4);
        af[mi][kk] = *(const bf16x8*)(sA + (size_t)rr * 128 + (w ^ ((rr & 7) << 4)));
        int r2 = wn * 64 + mi * 16 + (lane & 15);
        bfr[mi][kk] = *(const bf16x8*)(sB + (size_t)r2 * 128 + (w ^ ((r2 & 7) << 4)));
      }
#pragma unroll
    for (int kk = 0; kk < 2; ++kk)
#pragma unroll
      for (int mi = 0; mi < 4; ++mi)
#pragma unroll
        for (int ni = 0; ni < 4; ++ni)
          acc[mi][ni] =
              __builtin_amdgcn_mfma_f32_16x16x32_bf16(af[mi][kk], bfr[ni][kk], acc[mi][ni], 0, 0, 0);
    __syncthreads();
  }

  float bs[4];
#pragma unroll
  for (int ni = 0; ni < 4; ++ni) bs[ni] = q_b[n0 + wn * 64 + ni * 16 + (lane & 15)];
#pragma unroll
  for (int mi = 0; mi < 4; ++mi)
#pragma unroll
    for (int ni = 0; ni < 4; ++ni)
#pragma unroll
      for (int j = 0; j < 4; ++j) {
        int row = wm * 64 + mi * 16 + ((lane >> 4) << 2) + j;
        int col = wn * 64 + ni * 16 + (lane & 15);
        int m = m0 + row, n = n0 + col;
        float val = (acc[mi][ni][j] + bs[ni]) * SCALE_F;
        int bb = m >> 11, t = m & 2047, hh = n >> 6, d = n & 63;
        Qout[(((size_t)(bb * 16 + hh) * 2048 + t) << 6) + d] = (bf16)val;
      }
}

// Out-proj + residual: out(B,C,T) = inpt + (Y @ out_w^T + out_b)^T  (R5 exact)
__global__ __launch_bounds__(256, 2) void gemm_outres(const bf16* __restrict__ A,
                                                      const bf16* __restrict__ Bw,
                                                      const float* __restrict__ bias,
                                                      const float* __restrict__ inpt,
                                                      float* __restrict__ out) {
  __shared__ __align__(16) char smem[65536];  // loop: sA=[0,16K), sB=[16K,32K); epi: all 64K
  char* sA = smem;
  char* sB = smem + 16384;
  const int tid = threadIdx.x;
  const int lane = tid & 63;
  const int wave = tid >> 6;
  const int wm = wave >> 1, wn = wave & 1;
  const int g = lane >> 4, lr = lane & 15;
  const int m0 = blockIdx.x * 128, n0 = blockIdx.y * 128;
  f32x4 acc[4][4] = {};

  for (int kt = 0; kt < 1024; kt += 64) {
#pragma unroll
    for (int j = 0; j < 4; ++j) {
      int i = tid + j * 256;
      int r = i >> 3, q = i & 7;
      int so = (q ^ (r & 7)) << 4;
      load_lds16((const char*)(A + (size_t)(m0 + r) * 1024 + kt) + so, sA + (size_t)i * 16);
      load_lds16((const char*)(Bw + (size_t)(n0 + r) * 1024 + kt) + so, sB + (size_t)i * 16);
    }
    asm volatile("s_waitcnt vmcnt(0)" ::: "memory");
    __syncthreads();
    bf16x8 af[4][2], bfr[4][2];
#pragma unroll
    for (int mi = 0; mi < 4; ++mi)
#pragma unroll
      for (int kk = 0; kk < 2; ++kk) {
        int rr = wm * 64 + mi * 16 + lr;
        int w = kk * 64 + (g << 4);
        af[mi][kk] = *(const bf16x8*)(sA + (size_t)rr * 128 + (w ^ ((rr & 7) << 4)));
        int r2 = wn * 64 + mi * 16 + lr;
        bfr[mi][kk] = *(const bf16x8*)(sB + (size_t)r2 * 128 + (w ^ ((r2 & 7) << 4)));
      }
#pragma unroll
    for (int kk = 0; kk < 2; ++kk)
#pragma unroll
      for (int mi = 0; mi < 4; ++mi)
#pragma unroll
        for (int ni = 0; ni < 4; ++ni)
          acc[mi][ni] =
              __builtin_amdgcn_mfma_f32_16x16x32_bf16(af[mi][kk], bfr[ni][kk], acc[mi][ni], 0, 0, 0);
    __syncthreads();
  }

  float bs[4];
#pragma unroll
  for (int ni = 0; ni < 4; ++ni) bs[ni] = bias[n0 + wn * 64 + ni * 16 + lr];

  // acc -> LDS [c][t] f32 (row 512B, XOR-swizzled by c)
#pragma unroll
  for (int mi = 0; mi < 4; ++mi)
#pragma unroll
    for (int ni = 0; ni < 4; ++ni) {
      int c_l = wn * 64 + ni * 16 + lr;
      int tb = (wm * 64 + mi * 16 + g * 4) * 4;  // byte offset of token-quad (16B aligned)
      f32x4 v;
#pragma unroll
      for (int j = 0; j < 4; ++j) v[j] = acc[mi][ni][j] + bs[ni];
      *(f32x4*)(smem + (size_t)c_l * 512 + (tb ^ ((c_l & 31) << 4))) = v;
    }
  __syncthreads();

  // coalesced read-add-write: 4 passes x (32 c-rows, 8 lanes x 16B contiguous per row)
  const int c_r = tid >> 3;
  const int tcol = (tid & 7) * 16;  // byte
  const int b = m0 >> 11, m0t = m0 & 2047;
#pragma unroll
  for (int p = 0; p < 4; ++p) {
    int c = p * 32 + c_r;
    size_t grow = ((size_t)b * 1024 + n0 + c) * 2048 + m0t;  // float index of row base
#pragma unroll
    for (int q = 0; q < 4; ++q) {
      int t = tcol + q * 128;  // byte within 512B row
      f32x4 z = *(const f32x4*)(smem + (size_t)c * 512 + (t ^ ((c & 31) << 4)));
      f32x4 iv = *(const f32x4*)(inpt + grow + (t >> 2));
      f32x4 w;
#pragma unroll
      for (int j = 0; j < 4; ++j) w[j] = iv[j] + z[j];
      *(f32x4*)(out + grow + (t >> 2)) = w;
    }
  }
}

// ---------------- attention v4: barrier-free flash per wave (R5 exact) ----------------
struct Frags {
  bf16x8 ka[2][2];
  bf16x8 va[4];
};

__device__ __forceinline__ void load_frags(Frags& f, const char* lds, int G, int lr, int g) {
  const int swz = (lr & 7) << 4;
#pragma unroll
  for (int m = 0; m < 2; ++m)
#pragma unroll
    for (int kk = 0; kk < 2; ++kk)
      f.ka[m][kk] =
          *(const bf16x8*)(lds + (size_t)(G * 32 + m * 16 + lr) * 128 + ((kk * 64 + g * 16) ^ swz));
#pragma unroll
  for (int db = 0; db < 4; ++db)
    f.va[db] = *(const bf16x8*)(lds + 65536 + (size_t)(db * 16 + lr) * 1024 +
                                ((G * 64 + g * 16) ^ swz));
}

__device__ __forceinline__ void compute_group(const Frags& f, const bf16x8 (&qf)[4][2],
                                              f32x4 (&oacc)[4][4], float (&psum)[4]) {
  f32x4 sa[4][2] = {};
#pragma unroll
  for (int s = 0; s < 4; ++s)
#pragma unroll
    for (int m = 0; m < 2; ++m) {
      sa[s][m] = __builtin_amdgcn_mfma_f32_16x16x32_bf16(f.ka[m][0], qf[s][0], sa[s][m], 0, 0, 0);
      sa[s][m] = __builtin_amdgcn_mfma_f32_16x16x32_bf16(f.ka[m][1], qf[s][1], sa[s][m], 0, 0, 0);
    }
  bf16x8 pb[4];
#pragma unroll
  for (int s = 0; s < 4; ++s)
#pragma unroll
    for (int m = 0; m < 2; ++m)
#pragma unroll
      for (int j = 0; j < 4; ++j) {
        float p = __expf(sa[s][m][j] - 16.0f);
        psum[s] += p;
        pb[s][m * 4 + j] = (bf16)p;
      }
#pragma unroll
  for (int s = 0; s < 4; ++s)
#pragma unroll
    for (int db = 0; db < 4; ++db)
      oacc[s][db] = __builtin_amdgcn_mfma_f32_16x16x32_bf16(f.va[db], pb[s], oacc[s][db], 0, 0, 0);
}

__global__ __launch_bounds__(512, 2) void attn_kernel(const bf16* __restrict__ Q,
                                                      const bf16* __restrict__ Kw,
                                                      const bf16* __restrict__ Vt,
                                                      bf16* __restrict__ Y) {
  __shared__ __align__(16) char lds[131072];
  const int tid = threadIdx.x;
  const int lane = tid & 63;
  const int wv = tid >> 6;
  const int g = lane >> 4, lr = lane & 15;
  const int bix = blockIdx.x;
  const int b = bix >> 6, h = (bix >> 2) & 15, tc = bix & 3;

  const bf16* Kh = Kw + (size_t)h * 512 * 64;
  const bf16* Vh = Vt + (size_t)h * 64 * 512;
#pragma unroll
  for (int j = 0; j < 8; ++j) {
    int i = tid + j * 512;
    int r = i >> 3, c = i & 7;
    load_lds16((const char*)Kh + r * 128 + ((c * 16) ^ ((r & 7) << 4)), lds + (size_t)i * 16);
  }
#pragma unroll
  for (int j = 0; j < 8; ++j) {
    int i = tid + j * 512;
    int r = i >> 6, c = i & 63;
    load_lds16((const char*)Vh + r * 1024 + ((c * 16) ^ ((r & 7) << 4)),
               lds + 65536 + (size_t)i * 16);
  }

  const int tb = tc * 512 + wv * 64;
  const bf16* Qh = Q + ((size_t)(b * 16 + h) * 2048 + tb) * 64;
  bf16x8 qf[4][2];
#pragma unroll
  for (int s = 0; s < 4; ++s)
#pragma unroll
    for (int kk = 0; kk < 2; ++kk)
      qf[s][kk] = *(const bf16x8*)((const char*)Qh + (s * 16 + lr) * 128 + kk * 64 + g * 16);

  asm volatile("s_waitcnt vmcnt(0)" ::: "memory");
  __syncthreads();  // the only barrier

  f32x4 oacc[4][4] = {};  // [set][db]
  float psum[4] = {};

  Frags fA, fB;
  load_frags(fA, lds, 0, lr, g);
#pragma unroll 1
  for (int G = 0; G < 16; G += 2) {
    load_frags(fB, lds, G + 1, lr, g);
    compute_group(fA, qf, oacc, psum);
    if (G + 2 < 16) load_frags(fA, lds, G + 2, lr, g);
    compute_group(fB, qf, oacc, psum);
  }

  // finalize: sum over lane quarters, normalize, store
#pragma unroll
  for (int s = 0; s < 4; ++s) {
    float ssum = psum[s];
    ssum += __shfl_xor(ssum, 16);
    ssum += __shfl_xor(ssum, 32);
    float inv = 1.0f / ssum;
    int t = tb + s * 16 + lr;
    char* yrow = (char*)Y + ((size_t)(b * 2048 + t) * 1024 + h * 64) * 2;
#pragma unroll
    for (int db = 0; db < 4; ++db) {
      bf16x4 w;
#pragma unroll
      for (int j = 0; j < 4; ++j) w[j] = (bf16)(oacc[s][db][j] * inv);
      *(bf16x4*)(yrow + (db * 16 + g * 4) * 2) = w;
    }
  }
}

// ---------------- launch ----------------

extern "C" void kernel_launch(void* const* d_in, const int* in_sizes, int n_in, void* d_out,
                              int out_size, void* d_ws, size_t ws_size, hipStream_t stream) {
  const float* inpt = (const float*)d_in[0];
  const float* aux = (const float*)d_in[1];
  const float* q_w = (const float*)d_in[2];
  const float* q_b = (const float*)d_in[3];
  const float* kv_w = (const float*)d_in[4];
  const float* kv_b = (const float*)d_in[5];
  const float* out_w = (const float*)d_in[6];
  const float* out_b = (const float*)d_in[7];
  float* out = (float*)d_out;
  char* ws = (char*)d_ws;
  bf16* X = (bf16*)(ws + 0);              // 16MB: X bf16 ; reused as attn-out Y
  bf16* QZ = (bf16*)(ws + (16u << 20));   // 16MB: Q (B,H,T,D)
  bf16* qwb = (bf16*)(ws + (32u << 20));  // 2MB
  bf16* owb = (bf16*)(ws + (34u << 20));  // 2MB
  bf16* Kws = (bf16*)(ws + (36u << 20));  // 1MB (H,L,D)
  bf16* Vtw = (bf16*)(ws + (37u << 20));  // 1MB (H,D,L) permuted slots

  prep<<<10240, 256, 0, stream>>>(q_w, qwb, out_w, owb, inpt, X);
  gemm_kv<<<64, 256, 0, stream>>>(aux, kv_w, kv_b, Kws, Vtw);
  gemm_q<<<512, 256, 0, stream>>>(X, qwb, q_b, QZ);
  attn_kernel<<<256, 512, 0, stream>>>(QZ, Kws, Vtw, X /* Y reuses X */);
  gemm_outres<<<dim3(64, 8), 256, 0, stream>>>(X, owb, out_b, inpt, out);
}